// Round 9
// baseline (143.542 us; speedup 1.0000x reference)
//
#include <hip/hip_runtime.h>
#include <hip/hip_bf16.h>
#include <math.h>
#include <stdint.h>

#define B 4
#define CLOW 512
#define CHIGH 256
#define KC 64
#define VC 64
#define N 4096  // 64*64 tokens

typedef __attribute__((ext_vector_type(8))) short bf16x8;
typedef __attribute__((ext_vector_type(4))) short bf16x4;
typedef __attribute__((ext_vector_type(4))) float f32x4;

__device__ inline unsigned short f2bf(float f) {
    union { float f; uint32_t u; } v; v.f = f;
    uint32_t u = v.u;
    u += 0x7fff + ((u >> 16) & 1);   // RNE
    return (unsigned short)(u >> 16);
}
__device__ inline float bf2f(unsigned short h) {
    union { uint32_t u; float f; } v; v.u = ((uint32_t)h) << 16;
    return v.f;
}
__device__ inline uint32_t packbf2(float a, float b) {
    union { __hip_bfloat16 h; unsigned short u; } ca, cb;
    ca.h = __float2bfloat16(a);
    cb.h = __float2bfloat16(b);
    return (uint32_t)ca.u | ((uint32_t)cb.u << 16);
}

#if __has_builtin(__builtin_amdgcn_exp2f)
#define EXP2(x) __builtin_amdgcn_exp2f(x)
#else
#define EXP2(x) exp2f(x)
#endif

// ---------------- QKV projection via split-bf16 MFMA ----------------
// z=0: Q from xh (C=256), pre-scaled by log2(e).
// z=1: K AND V fused from xl (C=512) — xl staged once, 6 MFMA/tile.
__global__ __launch_bounds__(256) void proj_mfma(
    const float* __restrict__ xl, const float* __restrict__ xh,
    const float* __restrict__ Wq, const float* __restrict__ bq,
    const float* __restrict__ Wk, const float* __restrict__ bk,
    const float* __restrict__ Wv, const float* __restrict__ bv,
    unsigned short* __restrict__ Qt, unsigned short* __restrict__ Kt,
    unsigned short* __restrict__ Vt)
{
    const int proj = blockIdx.z;
    const int b    = blockIdx.y;
    const int n0   = blockIdx.x * 64;
    const int tid  = threadIdx.x;
    const int wv   = tid >> 6;          // wave id 0..3
    const int lane = tid & 63;
    const int lo   = lane & 15;
    const int hi   = lane >> 4;         // 0..3
    const int hi8  = hi * 8;

    __shared__ unsigned short XtHi[64][40];
    __shared__ unsigned short XtLo[64][40];

    const int cR = tid >> 3;        // staging: chan 0..31 within chunk
    const int t8 = (tid & 7) * 8;   // staging: token offset 0..56

    if (proj == 0) {
        // ---------- Q ----------
        f32x4 acc[4];
        #pragma unroll
        for (int t = 0; t < 4; ++t)
            #pragma unroll
            for (int r = 0; r < 4; ++r) acc[t][r] = bq[wv*16 + hi*4 + r];

        for (int c0 = 0; c0 < CHIGH; c0 += 32) {
            const float* src = xh + ((size_t)b*CHIGH + c0 + cR)*N + n0 + t8;
            float4 v0 = *(const float4*)src;
            float4 v1 = *(const float4*)(src + 4);
            float vv[8] = {v0.x, v0.y, v0.z, v0.w, v1.x, v1.y, v1.z, v1.w};
            #pragma unroll
            for (int i = 0; i < 8; ++i) {
                unsigned short h = f2bf(vv[i]);
                XtHi[t8 + i][cR] = h;
                XtLo[t8 + i][cR] = f2bf(vv[i] - bf2f(h));
            }
            __syncthreads();

            const float* wp = Wq + (size_t)(wv*16 + lo)*CHIGH + c0 + hi8;
            float4 w0 = *(const float4*)wp;
            float4 w1 = *(const float4*)(wp + 4);
            float ww[8] = {w0.x, w0.y, w0.z, w0.w, w1.x, w1.y, w1.z, w1.w};
            bf16x8 ah, al;
            #pragma unroll
            for (int i = 0; i < 8; ++i) {
                unsigned short h = f2bf(ww[i]);
                ah[i] = (short)h;
                al[i] = (short)f2bf(ww[i] - bf2f(h));
            }

            #pragma unroll
            for (int t = 0; t < 4; ++t) {
                bf16x8 xhv = *(const bf16x8*)&XtHi[t*16 + lo][hi8];
                bf16x8 xlv = *(const bf16x8*)&XtLo[t*16 + lo][hi8];
                acc[t] = __builtin_amdgcn_mfma_f32_16x16x32_bf16(ah, xhv, acc[t], 0, 0, 0);
                acc[t] = __builtin_amdgcn_mfma_f32_16x16x32_bf16(ah, xlv, acc[t], 0, 0, 0);
                acc[t] = __builtin_amdgcn_mfma_f32_16x16x32_bf16(al, xhv, acc[t], 0, 0, 0);
            }
            __syncthreads();
        }
        const float qs = 1.4426950408889634f;   // log2(e): attn uses raw exp2
        #pragma unroll
        for (int t = 0; t < 4; ++t) {
            bf16x4 o;
            #pragma unroll
            for (int r = 0; r < 4; ++r) o[r] = (short)f2bf(acc[t][r] * qs);
            *(bf16x4*)&Qt[((size_t)b*N + n0 + t*16 + lo)*KC + wv*16 + hi*4] = o;
        }
    } else {
        // ---------- K + V fused (stage xl once) ----------
        f32x4 accK[4], accV[4];
        #pragma unroll
        for (int t = 0; t < 4; ++t)
            #pragma unroll
            for (int r = 0; r < 4; ++r) {
                accK[t][r] = bk[wv*16 + hi*4 + r];
                accV[t][r] = bv[wv*16 + hi*4 + r];
            }

        for (int c0 = 0; c0 < CLOW; c0 += 32) {
            const float* src = xl + ((size_t)b*CLOW + c0 + cR)*N + n0 + t8;
            float4 v0 = *(const float4*)src;
            float4 v1 = *(const float4*)(src + 4);
            float vv[8] = {v0.x, v0.y, v0.z, v0.w, v1.x, v1.y, v1.z, v1.w};
            #pragma unroll
            for (int i = 0; i < 8; ++i) {
                unsigned short h = f2bf(vv[i]);
                XtHi[t8 + i][cR] = h;
                XtLo[t8 + i][cR] = f2bf(vv[i] - bf2f(h));
            }
            __syncthreads();

            const float* wpk = Wk + (size_t)(wv*16 + lo)*CLOW + c0 + hi8;
            const float* wpv = Wv + (size_t)(wv*16 + lo)*CLOW + c0 + hi8;
            bf16x8 ahk, alk, ahv, alv;
            {
                float4 w0 = *(const float4*)wpk;
                float4 w1 = *(const float4*)(wpk + 4);
                float ww[8] = {w0.x,w0.y,w0.z,w0.w,w1.x,w1.y,w1.z,w1.w};
                #pragma unroll
                for (int i = 0; i < 8; ++i) {
                    unsigned short h = f2bf(ww[i]);
                    ahk[i] = (short)h;
                    alk[i] = (short)f2bf(ww[i] - bf2f(h));
                }
            }
            {
                float4 w0 = *(const float4*)wpv;
                float4 w1 = *(const float4*)(wpv + 4);
                float ww[8] = {w0.x,w0.y,w0.z,w0.w,w1.x,w1.y,w1.z,w1.w};
                #pragma unroll
                for (int i = 0; i < 8; ++i) {
                    unsigned short h = f2bf(ww[i]);
                    ahv[i] = (short)h;
                    alv[i] = (short)f2bf(ww[i] - bf2f(h));
                }
            }

            #pragma unroll
            for (int t = 0; t < 4; ++t) {
                bf16x8 xhv = *(const bf16x8*)&XtHi[t*16 + lo][hi8];
                bf16x8 xlv = *(const bf16x8*)&XtLo[t*16 + lo][hi8];
                accK[t] = __builtin_amdgcn_mfma_f32_16x16x32_bf16(ahk, xhv, accK[t], 0, 0, 0);
                accK[t] = __builtin_amdgcn_mfma_f32_16x16x32_bf16(ahk, xlv, accK[t], 0, 0, 0);
                accK[t] = __builtin_amdgcn_mfma_f32_16x16x32_bf16(alk, xhv, accK[t], 0, 0, 0);
                accV[t] = __builtin_amdgcn_mfma_f32_16x16x32_bf16(ahv, xhv, accV[t], 0, 0, 0);
                accV[t] = __builtin_amdgcn_mfma_f32_16x16x32_bf16(ahv, xlv, accV[t], 0, 0, 0);
                accV[t] = __builtin_amdgcn_mfma_f32_16x16x32_bf16(alv, xhv, accV[t], 0, 0, 0);
            }
            __syncthreads();
        }

        #pragma unroll
        for (int t = 0; t < 4; ++t) {
            bf16x4 o;
            #pragma unroll
            for (int r = 0; r < 4; ++r) o[r] = (short)f2bf(accK[t][r]);
            *(bf16x4*)&Kt[((size_t)b*N + n0 + t*16 + lo)*KC + wv*16 + hi*4] = o;
            #pragma unroll
            for (int r = 0; r < 4; ++r)
                Vt[((size_t)b*VC + wv*16 + hi*4 + r)*N + n0 + t*16 + lo] = f2bf(accV[t][r]);
        }
    }
}

// ---------------- Flash attention: QT=4, 16 waves/block, kv-split-16 ----------------
// Grid = 256 blocks (1/CU). xcd = bid&7; batch = xcd>>1 (XCD-affinity -> K/V L2-res).
// Block = 16 waves (1024 thr) sharing q-rows [q0, q0+64); wave w owns kv [w*256, +256).
// 4 waves/SIMD (vs 2 in R7) for latency hiding at unchanged per-wave intensity.
// Combine: two-phase tree reusing one 8-slab LDS buffer (16 -> 8 -> final).
#define WSPLIT 16
#define QT 4
__global__ __launch_bounds__(1024, 4) void attn(
    const unsigned short* __restrict__ Qt,
    const unsigned short* __restrict__ Kt,
    const unsigned short* __restrict__ Vt,
    float* __restrict__ ctx)
{
    const int bid = blockIdx.x;
    const int xcd = bid & 7;
    const int b   = xcd >> 1;                          // batch <- XCD pair
    const int q0  = ((bid >> 3) * 2 + (xcd & 1)) * 64; // q-tile base (64 rows)

    const int tid  = threadIdx.x;
    const int wv   = tid >> 6;    // 0..15
    const int lane = tid & 63;
    const int lo   = lane & 15;
    const int hi   = lane >> 4;   // 0..3

    __shared__ float Olds[8][64][68];    // 139 KB slab buffer (reused across phases)
    __shared__ float llds[WSPLIT][64];

    // Q B-frags: [kt][qt]; lane holds Q[q0+qt*16+lo][kt*32+hi*8 ..+8)
    bf16x8 qf[2][QT];
    #pragma unroll
    for (int qt = 0; qt < QT; ++qt) {
        const unsigned short* qp = Qt + ((size_t)b*N + q0 + qt*16 + lo)*KC + hi*8;
        qf[0][qt] = *(const bf16x8*)(qp);
        qf[1][qt] = *(const bf16x8*)(qp + 32);
    }

    f32x4 O[4][QT] = {};           // [v-subtile][q-subtile]
    float l_run[QT] = {};

    const unsigned short* Kb = Kt + (size_t)b*N*KC;
    const unsigned short* Vb = Vt + (size_t)b*VC*N;

    const int kv0   = wv * (N/WSPLIT);
    const int kvend = kv0 + (N/WSPLIT);

    for (int kv = kv0; kv < kvend; kv += 32) {
        // ---- K A-frags + V B-frags for this 32-kv chunk (L2-resident) ----
        bf16x8 ka[2][2], va[4];
        #pragma unroll
        for (int j = 0; j < 2; ++j) {
            const unsigned short* kp = Kb + (size_t)(kv + j*16 + lo)*KC + hi*8;
            ka[j][0] = *(const bf16x8*)(kp);
            ka[j][1] = *(const bf16x8*)(kp + 32);
        }
        #pragma unroll
        for (int vt = 0; vt < 4; ++vt)
            va[vt] = *(const bf16x8*)(Vb + (size_t)(vt*16 + lo)*N + kv + hi*8);

        #pragma unroll
        for (int qt = 0; qt < QT; ++qt) {
            // ---- S^T = K · Q^T : lane(hi,lo) reg r = P^T[4hi+r][q=lo] ----
            f32x4 st[2];
            #pragma unroll
            for (int j = 0; j < 2; ++j) {
                f32x4 z = {};
                z     = __builtin_amdgcn_mfma_f32_16x16x32_bf16(ka[j][0], qf[0][qt], z, 0, 0, 0);
                st[j] = __builtin_amdgcn_mfma_f32_16x16x32_bf16(ka[j][1], qf[1][qt], z, 0, 0, 0);
            }
            // ---- p = 2^s (Q pre-scaled by log2e); in-lane bf16 pack ----
            uint32_t pk[2][2];
            #pragma unroll
            for (int j = 0; j < 2; ++j) {
                float p0 = EXP2(st[j][0]);
                float p1 = EXP2(st[j][1]);
                float p2 = EXP2(st[j][2]);
                float p3 = EXP2(st[j][3]);
                l_run[qt] += (p0 + p1) + (p2 + p3);
                pk[j][0] = packbf2(p0, p1);
                pk[j][1] = packbf2(p2, p3);
            }
            // ---- P^T(D-layout) -> P(A-frag) via 8 shfl + selects (R4-validated) ----
            union { int w[4]; bf16x8 v; } pa;
            #pragma unroll
            for (int w = 0; w < 4; ++w) {
                int src = (2*(hi & 1) + (w >> 1))*16 + lo;
                int t0 = __shfl((int)pk[0][w & 1], src);
                int t1 = __shfl((int)pk[1][w & 1], src);
                pa.w[w] = (hi < 2) ? t0 : t1;
            }
            // ---- PV ----
            #pragma unroll
            for (int vt = 0; vt < 4; ++vt)
                O[vt][qt] = __builtin_amdgcn_mfma_f32_16x16x32_bf16(pa.v, va[vt], O[vt][qt], 0, 0, 0);
        }
    }

    // ---- reduce l across the 4 hi-groups; every lane gets l[q=lo] ----
    #pragma unroll
    for (int qt = 0; qt < QT; ++qt) {
        float s = l_run[qt];
        s += __shfl_xor(s, 16);
        s += __shfl_xor(s, 32);
        l_run[qt] = s;
        if (lane < 16) llds[wv][qt*16 + lo] = s;
    }

    // ---- phase 1: waves 8..15 publish partials ----
    if (wv >= 8) {
        #pragma unroll
        for (int qt = 0; qt < QT; ++qt)
            #pragma unroll
            for (int vt = 0; vt < 4; ++vt)
                #pragma unroll
                for (int r = 0; r < 4; ++r)
                    Olds[wv - 8][qt*16 + hi*4 + r][vt*16 + lo] = O[vt][qt][r];
    }
    __syncthreads();

    // ---- phase 2: waves 0..7 accumulate partner partials into registers ----
    if (wv < 8) {
        #pragma unroll
        for (int qt = 0; qt < QT; ++qt)
            #pragma unroll
            for (int vt = 0; vt < 4; ++vt)
                #pragma unroll
                for (int r = 0; r < 4; ++r)
                    O[vt][qt][r] += Olds[wv][qt*16 + hi*4 + r][vt*16 + lo];
    }
    __syncthreads();

    // ---- phase 3: waves 0..7 publish combined partials ----
    if (wv < 8) {
        #pragma unroll
        for (int qt = 0; qt < QT; ++qt)
            #pragma unroll
            for (int vt = 0; vt < 4; ++vt)
                #pragma unroll
                for (int r = 0; r < 4; ++r)
                    Olds[wv][qt*16 + hi*4 + r][vt*16 + lo] = O[vt][qt][r];
    }
    __syncthreads();

    // ---- phase 4: final 8-way combine, normalize, store (1024 thr = 64 rows x 16 col4) ----
    {
        const int row = tid >> 4;          // 0..63
        const int c4  = (tid & 15) * 4;    // 0..60
        float L = 0.f;
        #pragma unroll
        for (int w = 0; w < WSPLIT; ++w) L += llds[w][row];
        float4 o = {0.f, 0.f, 0.f, 0.f};
        #pragma unroll
        for (int w = 0; w < 8; ++w) {
            float4 ow = *(const float4*)&Olds[w][row][c4];
            o.x += ow.x; o.y += ow.y; o.z += ow.z; o.w += ow.w;
        }
        float rL = 1.0f / L;
        o.x *= rL; o.y *= rL; o.z *= rL; o.w *= rL;
        *(float4*)&ctx[((size_t)b*N + q0 + row)*VC + c4] = o;
    }
}

// ---------------- Output projection + residual via split-bf16 MFMA ----------------
// Out[o][n] = sum_v Wo[o][v]*ctx[n][v] + bo[o] + xh[o][n]
// A-frag = Wo row-major (contiguous), B-frag = ctx token-major (contiguous) -> no LDS.
__global__ __launch_bounds__(256) void oproj_mfma(
    const float* __restrict__ ctx, const float* __restrict__ Wo,
    const float* __restrict__ bo, const float* __restrict__ xh,
    float* __restrict__ out)
{
    const int b    = blockIdx.y;
    const int n0   = blockIdx.x * 64;
    const int tid  = threadIdx.x;
    const int wv   = tid >> 6;          // wave -> chans [wv*64, +64)
    const int lane = tid & 63;
    const int lo   = lane & 15;
    const int hi   = lane >> 4;
    const int hi8  = hi * 8;

    for (int tt = 0; tt < 4; ++tt) {
        // ---- B-frags: ctx[n0+tt*16+lo][j*32+hi8 ..+8), split hi/lo ----
        bf16x8 bh[2], bl[2];
        const float* cp = ctx + ((size_t)b*N + n0 + tt*16 + lo)*VC + hi8;
        #pragma unroll
        for (int j = 0; j < 2; ++j) {
            float4 c0 = *(const float4*)(cp + j*32);
            float4 c1 = *(const float4*)(cp + j*32 + 4);
            float cc[8] = {c0.x,c0.y,c0.z,c0.w,c1.x,c1.y,c1.z,c1.w};
            #pragma unroll
            for (int i = 0; i < 8; ++i) {
                unsigned short h = f2bf(cc[i]);
                bh[j][i] = (short)h;
                bl[j][i] = (short)f2bf(cc[i] - bf2f(h));
            }
        }
        #pragma unroll
        for (int ct = 0; ct < 4; ++ct) {
            const int chan0 = wv*64 + ct*16;
            // ---- A-frags: Wo[chan0+lo][j*32+hi8 ..+8), split hi/lo (L1-resident) ----
            bf16x8 ah[2], al[2];
            const float* wp = Wo + (size_t)(chan0 + lo)*VC + hi8;
            #pragma unroll
            for (int j = 0; j < 2; ++j) {
                float4 w0 = *(const float4*)(wp + j*32);
                float4 w1 = *(const float4*)(wp + j*32 + 4);
                float ww[8] = {w0.x,w0.y,w0.z,w0.w,w1.x,w1.y,w1.z,w1.w};
                #pragma unroll
                for (int i = 0; i < 8; ++i) {
                    unsigned short h = f2bf(ww[i]);
                    ah[j][i] = (short)h;
                    al[j][i] = (short)f2bf(ww[i] - bf2f(h));
                }
            }
            f32x4 acc;
            #pragma unroll
            for (int r = 0; r < 4; ++r) acc[r] = bo[chan0 + hi*4 + r];
            #pragma unroll
            for (int j = 0; j < 2; ++j) {
                acc = __builtin_amdgcn_mfma_f32_16x16x32_bf16(ah[j], bh[j], acc, 0, 0, 0);
                acc = __builtin_amdgcn_mfma_f32_16x16x32_bf16(ah[j], bl[j], acc, 0, 0, 0);
                acc = __builtin_amdgcn_mfma_f32_16x16x32_bf16(al[j], bh[j], acc, 0, 0, 0);
            }
            // ---- residual + store: D[row=4hi+r][col=lo], row=chan, col=token ----
            #pragma unroll
            for (int r = 0; r < 4; ++r) {
                size_t idx = ((size_t)b*CHIGH + chan0 + hi*4 + r)*N + n0 + tt*16 + lo;
                out[idx] = acc[r] + xh[idx];
            }
        }
    }
}

extern "C" void kernel_launch(void* const* d_in, const int* in_sizes, int n_in,
                              void* d_out, int out_size, void* d_ws, size_t ws_size,
                              hipStream_t stream) {
    const float* xl = (const float*)d_in[0];
    const float* xh = (const float*)d_in[1];
    const float* Wq = (const float*)d_in[2];
    const float* bq = (const float*)d_in[3];
    const float* Wk = (const float*)d_in[4];
    const float* bk = (const float*)d_in[5];
    const float* Wv = (const float*)d_in[6];
    const float* bv = (const float*)d_in[7];
    const float* Wo = (const float*)d_in[8];
    const float* bo = (const float*)d_in[9];
    float* out = (float*)d_out;

    unsigned short* Qt = (unsigned short*)d_ws;                 // [B][N][64] bf16 (x log2e)
    unsigned short* Kt = Qt + (size_t)B*N*KC;                   // [B][N][64] bf16
    unsigned short* Vt = Kt + (size_t)B*N*KC;                   // [B][64][N] bf16
    float*         ctxp = (float*)(Vt + (size_t)B*VC*N);        // [B][N][64] f32

    hipLaunchKernelGGL(proj_mfma, dim3(N/64, B, 2), dim3(256), 0, stream,
                       xl, xh, Wq, bq, Wk, bk, Wv, bv, Qt, Kt, Vt);
    hipLaunchKernelGGL(attn, dim3(256), dim3(1024), 0, stream,
                       Qt, Kt, Vt, ctxp);
    hipLaunchKernelGGL(oproj_mfma, dim3(N/64, B), dim3(256), 0, stream,
                       ctxp, Wo, bo, xh, out);
}

// Round 10
// 76.969 us; speedup vs baseline: 1.8649x; 1.8649x over previous
//
#include <hip/hip_runtime.h>
#include <hip/hip_bf16.h>
#include <math.h>
#include <stdint.h>

#define B 4
#define CLOW 512
#define CHIGH 256
#define KC 64
#define VC 64
#define N 4096  // 64*64 tokens

typedef __attribute__((ext_vector_type(8))) short bf16x8;
typedef __attribute__((ext_vector_type(4))) short bf16x4;
typedef __attribute__((ext_vector_type(4))) float f32x4;

__device__ inline unsigned short f2bf(float f) {
    union { float f; uint32_t u; } v; v.f = f;
    uint32_t u = v.u;
    u += 0x7fff + ((u >> 16) & 1);   // RNE
    return (unsigned short)(u >> 16);
}
__device__ inline float bf2f(unsigned short h) {
    union { uint32_t u; float f; } v; v.u = ((uint32_t)h) << 16;
    return v.f;
}
__device__ inline uint32_t packbf2(float a, float b) {
    union { __hip_bfloat16 h; unsigned short u; } ca, cb;
    ca.h = __float2bfloat16(a);
    cb.h = __float2bfloat16(b);
    return (uint32_t)ca.u | ((uint32_t)cb.u << 16);
}

#if __has_builtin(__builtin_amdgcn_exp2f)
#define EXP2(x) __builtin_amdgcn_exp2f(x)
#else
#define EXP2(x) exp2f(x)
#endif

// ================= Fragment-major layouts (so attn loads are base + lane*16B) ====
// Kf[b][tile16][m][lane][8] : elem K[tile*16+lo][m*32+hi*8+e],   lane = hi*16+lo
// Qf[b][tile16][kt][lane][8]: elem Q[tile*16+lo][kt*32+hi*8+e]   (pre-scaled log2e)
// Vf[b][tile32][vt][lane][8]: elem V[chan=vt*16+lo][tile*32+hi*8+e]
// Per-batch sizes: K/Q: 256 tiles * 1024 elems; V: 128 tiles * 2048 elems (= N*64).

// ---------------- QKV projection via split-bf16 MFMA ----------------
// z=0: Q from xh (C=256), pre-scaled by log2(e).
// z=1: K AND V fused from xl (C=512) — xl staged once, 6 MFMA/tile.
__global__ __launch_bounds__(256) void proj_mfma(
    const float* __restrict__ xl, const float* __restrict__ xh,
    const float* __restrict__ Wq, const float* __restrict__ bq,
    const float* __restrict__ Wk, const float* __restrict__ bk,
    const float* __restrict__ Wv, const float* __restrict__ bv,
    unsigned short* __restrict__ Qt, unsigned short* __restrict__ Kt,
    unsigned short* __restrict__ Vt)
{
    const int proj = blockIdx.z;
    const int b    = blockIdx.y;
    const int n0   = blockIdx.x * 64;
    const int tid  = threadIdx.x;
    const int wv   = tid >> 6;          // wave id 0..3
    const int lane = tid & 63;
    const int lo   = lane & 15;
    const int hi   = lane >> 4;         // 0..3
    const int hi8  = hi * 8;

    __shared__ unsigned short XtHi[64][40];
    __shared__ unsigned short XtLo[64][40];

    const int cR = tid >> 3;        // staging: chan 0..31 within chunk
    const int t8 = (tid & 7) * 8;   // staging: token offset 0..56

    // fragment-store helpers (see layout comment):
    // K/Q: addr = ((b*256 + tile)*2 + (wv>>1))*512 + (((wv*2+(hi>>1))&3)*16 + lo)*8 + (hi&1)*4
    const size_t kqFragOff = (size_t)((((wv*2 + (hi>>1)) & 3)*16 + lo)*8 + (hi&1)*4);

    if (proj == 0) {
        // ---------- Q ----------
        f32x4 acc[4];
        #pragma unroll
        for (int t = 0; t < 4; ++t)
            #pragma unroll
            for (int r = 0; r < 4; ++r) acc[t][r] = bq[wv*16 + hi*4 + r];

        for (int c0 = 0; c0 < CHIGH; c0 += 32) {
            const float* src = xh + ((size_t)b*CHIGH + c0 + cR)*N + n0 + t8;
            float4 v0 = *(const float4*)src;
            float4 v1 = *(const float4*)(src + 4);
            float vv[8] = {v0.x, v0.y, v0.z, v0.w, v1.x, v1.y, v1.z, v1.w};
            #pragma unroll
            for (int i = 0; i < 8; ++i) {
                unsigned short h = f2bf(vv[i]);
                XtHi[t8 + i][cR] = h;
                XtLo[t8 + i][cR] = f2bf(vv[i] - bf2f(h));
            }
            __syncthreads();

            const float* wp = Wq + (size_t)(wv*16 + lo)*CHIGH + c0 + hi8;
            float4 w0 = *(const float4*)wp;
            float4 w1 = *(const float4*)(wp + 4);
            float ww[8] = {w0.x, w0.y, w0.z, w0.w, w1.x, w1.y, w1.z, w1.w};
            bf16x8 ah, al;
            #pragma unroll
            for (int i = 0; i < 8; ++i) {
                unsigned short h = f2bf(ww[i]);
                ah[i] = (short)h;
                al[i] = (short)f2bf(ww[i] - bf2f(h));
            }

            #pragma unroll
            for (int t = 0; t < 4; ++t) {
                bf16x8 xhv = *(const bf16x8*)&XtHi[t*16 + lo][hi8];
                bf16x8 xlv = *(const bf16x8*)&XtLo[t*16 + lo][hi8];
                acc[t] = __builtin_amdgcn_mfma_f32_16x16x32_bf16(ah, xhv, acc[t], 0, 0, 0);
                acc[t] = __builtin_amdgcn_mfma_f32_16x16x32_bf16(ah, xlv, acc[t], 0, 0, 0);
                acc[t] = __builtin_amdgcn_mfma_f32_16x16x32_bf16(al, xhv, acc[t], 0, 0, 0);
            }
            __syncthreads();
        }
        const float qs = 1.4426950408889634f;   // log2(e): attn uses raw exp2
        #pragma unroll
        for (int t = 0; t < 4; ++t) {
            bf16x4 o;
            #pragma unroll
            for (int r = 0; r < 4; ++r) o[r] = (short)f2bf(acc[t][r] * qs);
            size_t base = (((size_t)b*256 + (n0>>4) + t)*2 + (wv>>1))*512;
            *(bf16x4*)&Qt[base + kqFragOff] = o;
        }
    } else {
        // ---------- K + V fused (stage xl once) ----------
        f32x4 accK[4], accV[4];
        #pragma unroll
        for (int t = 0; t < 4; ++t)
            #pragma unroll
            for (int r = 0; r < 4; ++r) {
                accK[t][r] = bk[wv*16 + hi*4 + r];
                accV[t][r] = bv[wv*16 + hi*4 + r];
            }

        for (int c0 = 0; c0 < CLOW; c0 += 32) {
            const float* src = xl + ((size_t)b*CLOW + c0 + cR)*N + n0 + t8;
            float4 v0 = *(const float4*)src;
            float4 v1 = *(const float4*)(src + 4);
            float vv[8] = {v0.x, v0.y, v0.z, v0.w, v1.x, v1.y, v1.z, v1.w};
            #pragma unroll
            for (int i = 0; i < 8; ++i) {
                unsigned short h = f2bf(vv[i]);
                XtHi[t8 + i][cR] = h;
                XtLo[t8 + i][cR] = f2bf(vv[i] - bf2f(h));
            }
            __syncthreads();

            const float* wpk = Wk + (size_t)(wv*16 + lo)*CLOW + c0 + hi8;
            const float* wpv = Wv + (size_t)(wv*16 + lo)*CLOW + c0 + hi8;
            bf16x8 ahk, alk, ahv, alv;
            {
                float4 w0 = *(const float4*)wpk;
                float4 w1 = *(const float4*)(wpk + 4);
                float ww[8] = {w0.x,w0.y,w0.z,w0.w,w1.x,w1.y,w1.z,w1.w};
                #pragma unroll
                for (int i = 0; i < 8; ++i) {
                    unsigned short h = f2bf(ww[i]);
                    ahk[i] = (short)h;
                    alk[i] = (short)f2bf(ww[i] - bf2f(h));
                }
            }
            {
                float4 w0 = *(const float4*)wpv;
                float4 w1 = *(const float4*)(wpv + 4);
                float ww[8] = {w0.x,w0.y,w0.z,w0.w,w1.x,w1.y,w1.z,w1.w};
                #pragma unroll
                for (int i = 0; i < 8; ++i) {
                    unsigned short h = f2bf(ww[i]);
                    ahv[i] = (short)h;
                    alv[i] = (short)f2bf(ww[i] - bf2f(h));
                }
            }

            #pragma unroll
            for (int t = 0; t < 4; ++t) {
                bf16x8 xhv = *(const bf16x8*)&XtHi[t*16 + lo][hi8];
                bf16x8 xlv = *(const bf16x8*)&XtLo[t*16 + lo][hi8];
                accK[t] = __builtin_amdgcn_mfma_f32_16x16x32_bf16(ahk, xhv, accK[t], 0, 0, 0);
                accK[t] = __builtin_amdgcn_mfma_f32_16x16x32_bf16(ahk, xlv, accK[t], 0, 0, 0);
                accK[t] = __builtin_amdgcn_mfma_f32_16x16x32_bf16(alk, xhv, accK[t], 0, 0, 0);
                accV[t] = __builtin_amdgcn_mfma_f32_16x16x32_bf16(ahv, xhv, accV[t], 0, 0, 0);
                accV[t] = __builtin_amdgcn_mfma_f32_16x16x32_bf16(ahv, xlv, accV[t], 0, 0, 0);
                accV[t] = __builtin_amdgcn_mfma_f32_16x16x32_bf16(alv, xhv, accV[t], 0, 0, 0);
            }
            __syncthreads();
        }

        #pragma unroll
        for (int t = 0; t < 4; ++t) {
            // K fragment-major store
            bf16x4 o;
            #pragma unroll
            for (int r = 0; r < 4; ++r) o[r] = (short)f2bf(accK[t][r]);
            size_t kbase = (((size_t)b*256 + (n0>>4) + t)*2 + (wv>>1))*512;
            *(bf16x4*)&Kt[kbase + kqFragOff] = o;

            // V fragment-major store: chan = wv*16+hi*4+r, kv = n0+t*16+lo
            const int kvtile = (n0 >> 5) + (t >> 1);
            const int hi_f   = (t & 1)*2 + (lo >> 3);
            size_t vbase = ((size_t)b*128 + kvtile)*2048 + (size_t)wv*512
                         + (size_t)hi_f*128 + (size_t)(lo & 7);
            #pragma unroll
            for (int r = 0; r < 4; ++r)
                Vt[vbase + (size_t)(hi*4 + r)*8] = f2bf(accV[t][r]);
        }
    }
}

// ---------------- Flash attention: QT=4, 8 waves, kv-split-8, fragment-major loads --
// Grid = 256 blocks (1/CU). xcd = bid&7; batch = xcd>>1 (XCD-affinity -> K/V L2-res).
// Block = 8 waves (512 thr) sharing q-rows [q0, q0+64); wave w owns kv [w*512, +512).
// All K/V/Q loads are base + lane*16B (fragment-major) -> fully coalesced, no L1
// sector amplification (was 64 distinct cache lines per load instr in R8).
#define WSPLIT 8
#define QT 4
__global__ __launch_bounds__(512) void attn(
    const unsigned short* __restrict__ Qt,
    const unsigned short* __restrict__ Kt,
    const unsigned short* __restrict__ Vt,
    float* __restrict__ ctx)
{
    const int bid = blockIdx.x;
    const int xcd = bid & 7;
    const int b   = xcd >> 1;                          // batch <- XCD pair
    const int q0  = ((bid >> 3) * 2 + (xcd & 1)) * 64; // q-tile base (64 rows)

    const int tid  = threadIdx.x;
    const int wv   = tid >> 6;    // 0..7
    const int lane = tid & 63;
    const int lo   = lane & 15;
    const int hi   = lane >> 4;   // 0..3

    __shared__ float Olds[WSPLIT][64][68];   // 139 KB; pad 68 -> 272B row stride
    __shared__ float llds[WSPLIT][64];

    const unsigned short* Kb = Kt + (size_t)b*N*KC;
    const unsigned short* Vb = Vt + (size_t)b*VC*N;
    const unsigned short* Qb = Qt + (size_t)b*N*KC;

    // Q fragments (fragment-major: one dwordx4 per lane)
    bf16x8 qf[2][QT];
    #pragma unroll
    for (int qt = 0; qt < QT; ++qt) {
        #pragma unroll
        for (int kt = 0; kt < 2; ++kt)
            qf[kt][qt] = *(const bf16x8*)&Qb[(((size_t)(q0>>4) + qt)*2 + kt)*512 + lane*8];
    }

    f32x4 O[4][QT] = {};           // [v-subtile][q-subtile]
    float l_run[QT] = {};

    const int kv0   = wv * (N/WSPLIT);
    const int kvend = kv0 + (N/WSPLIT);

    for (int kv = kv0; kv < kvend; kv += 32) {
        // ---- K A-frags + V B-frags, all coalesced lane*16B loads ----
        bf16x8 ka[2][2], va[4];
        #pragma unroll
        for (int j = 0; j < 2; ++j)
            #pragma unroll
            for (int m = 0; m < 2; ++m)
                ka[j][m] = *(const bf16x8*)&Kb[(((size_t)(kv>>4) + j)*2 + m)*512 + lane*8];
        #pragma unroll
        for (int vt = 0; vt < 4; ++vt)
            va[vt] = *(const bf16x8*)&Vb[((size_t)(kv>>5))*2048 + vt*512 + lane*8];

        #pragma unroll
        for (int qt = 0; qt < QT; ++qt) {
            // ---- S^T = K · Q^T : lane(hi,lo) reg r = P^T[4hi+r][q=lo] ----
            f32x4 st[2];
            #pragma unroll
            for (int j = 0; j < 2; ++j) {
                f32x4 z = {};
                z     = __builtin_amdgcn_mfma_f32_16x16x32_bf16(ka[j][0], qf[0][qt], z, 0, 0, 0);
                st[j] = __builtin_amdgcn_mfma_f32_16x16x32_bf16(ka[j][1], qf[1][qt], z, 0, 0, 0);
            }
            // ---- p = 2^s (Q pre-scaled by log2e); in-lane bf16 pack ----
            uint32_t pk[2][2];
            #pragma unroll
            for (int j = 0; j < 2; ++j) {
                float p0 = EXP2(st[j][0]);
                float p1 = EXP2(st[j][1]);
                float p2 = EXP2(st[j][2]);
                float p3 = EXP2(st[j][3]);
                l_run[qt] += (p0 + p1) + (p2 + p3);
                pk[j][0] = packbf2(p0, p1);
                pk[j][1] = packbf2(p2, p3);
            }
            // ---- P^T(D-layout) -> P(A-frag) via 8 shfl + selects (R4-validated) ----
            union { int w[4]; bf16x8 v; } pa;
            #pragma unroll
            for (int w = 0; w < 4; ++w) {
                int src = (2*(hi & 1) + (w >> 1))*16 + lo;
                int t0 = __shfl((int)pk[0][w & 1], src);
                int t1 = __shfl((int)pk[1][w & 1], src);
                pa.w[w] = (hi < 2) ? t0 : t1;
            }
            // ---- PV ----
            #pragma unroll
            for (int vt = 0; vt < 4; ++vt)
                O[vt][qt] = __builtin_amdgcn_mfma_f32_16x16x32_bf16(pa.v, va[vt], O[vt][qt], 0, 0, 0);
        }
    }

    // ---- reduce l across the 4 hi-groups; every lane gets l[q=lo] ----
    #pragma unroll
    for (int qt = 0; qt < QT; ++qt) {
        float s = l_run[qt];
        s += __shfl_xor(s, 16);
        s += __shfl_xor(s, 32);
        l_run[qt] = s;
    }

    // ---- write per-wave partials ----
    #pragma unroll
    for (int qt = 0; qt < QT; ++qt) {
        #pragma unroll
        for (int vt = 0; vt < 4; ++vt)
            #pragma unroll
            for (int r = 0; r < 4; ++r)
                Olds[wv][qt*16 + hi*4 + r][vt*16 + lo] = O[vt][qt][r];
        if (lane < 16) llds[wv][qt*16 + lo] = l_run[qt];
    }
    __syncthreads();

    // ---- combine kv-split partials, normalize, store (512 thr = 64 rows x 8 col8) ----
    {
        const int row = tid >> 3;         // 0..63
        const int c8  = (tid & 7) * 8;    // 0..56
        float L = 0.f;
        #pragma unroll
        for (int w = 0; w < WSPLIT; ++w) L += llds[w][row];
        float4 a0 = {0.f,0.f,0.f,0.f}, a1 = {0.f,0.f,0.f,0.f};
        #pragma unroll
        for (int w = 0; w < WSPLIT; ++w) {
            float4 o0 = *(const float4*)&Olds[w][row][c8];
            float4 o1 = *(const float4*)&Olds[w][row][c8 + 4];
            a0.x += o0.x; a0.y += o0.y; a0.z += o0.z; a0.w += o0.w;
            a1.x += o1.x; a1.y += o1.y; a1.z += o1.z; a1.w += o1.w;
        }
        float rL = 1.0f / L;
        a0.x *= rL; a0.y *= rL; a0.z *= rL; a0.w *= rL;
        a1.x *= rL; a1.y *= rL; a1.z *= rL; a1.w *= rL;
        float* cp = &ctx[((size_t)b*N + q0 + row)*VC + c8];
        *(float4*)(cp)     = a0;
        *(float4*)(cp + 4) = a1;
    }
}

// ---------------- Output projection + residual via split-bf16 MFMA ----------------
// Out[o][n] = sum_v Wo[o][v]*ctx[n][v] + bo[o] + xh[o][n]
// A-frag = Wo row-major (contiguous), B-frag = ctx token-major (contiguous) -> no LDS.
__global__ __launch_bounds__(256) void oproj_mfma(
    const float* __restrict__ ctx, const float* __restrict__ Wo,
    const float* __restrict__ bo, const float* __restrict__ xh,
    float* __restrict__ out)
{
    const int b    = blockIdx.y;
    const int n0   = blockIdx.x * 64;
    const int tid  = threadIdx.x;
    const int wv   = tid >> 6;          // wave -> chans [wv*64, +64)
    const int lane = tid & 63;
    const int lo   = lane & 15;
    const int hi   = lane >> 4;
    const int hi8  = hi * 8;

    for (int tt = 0; tt < 4; ++tt) {
        // ---- B-frags: ctx[n0+tt*16+lo][j*32+hi8 ..+8), split hi/lo ----
        bf16x8 bh[2], bl[2];
        const float* cp = ctx + ((size_t)b*N + n0 + tt*16 + lo)*VC + hi8;
        #pragma unroll
        for (int j = 0; j < 2; ++j) {
            float4 c0 = *(const float4*)(cp + j*32);
            float4 c1 = *(const float4*)(cp + j*32 + 4);
            float cc[8] = {c0.x,c0.y,c0.z,c0.w,c1.x,c1.y,c1.z,c1.w};
            #pragma unroll
            for (int i = 0; i < 8; ++i) {
                unsigned short h = f2bf(cc[i]);
                bh[j][i] = (short)h;
                bl[j][i] = (short)f2bf(cc[i] - bf2f(h));
            }
        }
        #pragma unroll
        for (int ct = 0; ct < 4; ++ct) {
            const int chan0 = wv*64 + ct*16;
            // ---- A-frags: Wo[chan0+lo][j*32+hi8 ..+8), split hi/lo (L1-resident) ----
            bf16x8 ah[2], al[2];
            const float* wp = Wo + (size_t)(chan0 + lo)*VC + hi8;
            #pragma unroll
            for (int j = 0; j < 2; ++j) {
                float4 w0 = *(const float4*)(wp + j*32);
                float4 w1 = *(const float4*)(wp + j*32 + 4);
                float ww[8] = {w0.x,w0.y,w0.z,w0.w,w1.x,w1.y,w1.z,w1.w};
                #pragma unroll
                for (int i = 0; i < 8; ++i) {
                    unsigned short h = f2bf(ww[i]);
                    ah[j][i] = (short)h;
                    al[j][i] = (short)f2bf(ww[i] - bf2f(h));
                }
            }
            f32x4 acc;
            #pragma unroll
            for (int r = 0; r < 4; ++r) acc[r] = bo[chan0 + hi*4 + r];
            #pragma unroll
            for (int j = 0; j < 2; ++j) {
                acc = __builtin_amdgcn_mfma_f32_16x16x32_bf16(ah[j], bh[j], acc, 0, 0, 0);
                acc = __builtin_amdgcn_mfma_f32_16x16x32_bf16(ah[j], bl[j], acc, 0, 0, 0);
                acc = __builtin_amdgcn_mfma_f32_16x16x32_bf16(al[j], bh[j], acc, 0, 0, 0);
            }
            // ---- residual + store: D[row=4hi+r][col=lo], row=chan, col=token ----
            #pragma unroll
            for (int r = 0; r < 4; ++r) {
                size_t idx = ((size_t)b*CHIGH + chan0 + hi*4 + r)*N + n0 + tt*16 + lo;
                out[idx] = acc[r] + xh[idx];
            }
        }
    }
}

extern "C" void kernel_launch(void* const* d_in, const int* in_sizes, int n_in,
                              void* d_out, int out_size, void* d_ws, size_t ws_size,
                              hipStream_t stream) {
    const float* xl = (const float*)d_in[0];
    const float* xh = (const float*)d_in[1];
    const float* Wq = (const float*)d_in[2];
    const float* bq = (const float*)d_in[3];
    const float* Wk = (const float*)d_in[4];
    const float* bk = (const float*)d_in[5];
    const float* Wv = (const float*)d_in[6];
    const float* bv = (const float*)d_in[7];
    const float* Wo = (const float*)d_in[8];
    const float* bo = (const float*)d_in[9];
    float* out = (float*)d_out;

    unsigned short* Qt = (unsigned short*)d_ws;                 // [B][N*64] bf16 frag-major (x log2e)
    unsigned short* Kt = Qt + (size_t)B*N*KC;                   // [B][N*64] bf16 frag-major
    unsigned short* Vt = Kt + (size_t)B*N*KC;                   // [B][64*N] bf16 frag-major
    float*         ctxp = (float*)(Vt + (size_t)B*VC*N);        // [B][N][64] f32

    hipLaunchKernelGGL(proj_mfma, dim3(N/64, B, 2), dim3(256), 0, stream,
                       xl, xh, Wq, bq, Wk, bk, Wv, bv, Qt, Kt, Vt);
    hipLaunchKernelGGL(attn, dim3(256), dim3(512), 0, stream,
                       Qt, Kt, Vt, ctxp);
    hipLaunchKernelGGL(oproj_mfma, dim3(N/64, B), dim3(256), 0, stream,
                       ctxp, Wo, bo, xh, out);
}

// Round 12
// 76.280 us; speedup vs baseline: 1.8818x; 1.0090x over previous
//
#include <hip/hip_runtime.h>
#include <hip/hip_bf16.h>
#include <math.h>
#include <stdint.h>

#define B 4
#define CLOW 512
#define CHIGH 256
#define KC 64
#define VC 64
#define N 4096  // 64*64 tokens

typedef __attribute__((ext_vector_type(8))) short bf16x8;
typedef __attribute__((ext_vector_type(4))) short bf16x4;
typedef __attribute__((ext_vector_type(4))) float f32x4;

__device__ inline unsigned short f2bf(float f) {
    union { float f; uint32_t u; } v; v.f = f;
    uint32_t u = v.u;
    u += 0x7fff + ((u >> 16) & 1);   // RNE
    return (unsigned short)(u >> 16);
}
__device__ inline float bf2f(unsigned short h) {
    union { uint32_t u; float f; } v; v.u = ((uint32_t)h) << 16;
    return v.f;
}
__device__ inline uint32_t packbf2(float a, float b) {
    union { __hip_bfloat16 h; unsigned short u; } ca, cb;
    ca.h = __float2bfloat16(a);
    cb.h = __float2bfloat16(b);
    return (uint32_t)ca.u | ((uint32_t)cb.u << 16);
}
__device__ inline void bfsplit(float x, short* hi, short* lo) {
    union { __hip_bfloat16 h; unsigned short u; } c, d;
    c.h = __float2bfloat16(x);
    d.h = __float2bfloat16(x - __bfloat162float(c.h));
    *hi = (short)c.u; *lo = (short)d.u;
}

#if __has_builtin(__builtin_amdgcn_exp2f)
#define EXP2(x) __builtin_amdgcn_exp2f(x)
#else
#define EXP2(x) exp2f(x)
#endif

// ================= Fragment-major layouts (attn loads are base + lane*16B) ====
// Kf[b][tile16][m][lane][8] : elem K[tile*16+lo][m*32+hi*8+e],   lane = hi*16+lo
// Qf[b][tile16][kt][lane][8]: elem Q[tile*16+lo][kt*32+hi*8+e]   (pre-scaled log2e)
// Vf[b][tile32][vt][lane][8]: elem V[chan=vt*16+lo][tile*32+hi*8+e]

// ---------------- QKV projection via split-bf16 MFMA ----------------
// z=0: Q from xh (C=256). z=1: K AND V fused from xl (C=512), xl staged once.
// CSTEP=64, LDS stride 72 shorts (16B-aligned rows), block-XOR swizzle
// col' = col ^ ((row>>3)<<3): writes conflict-free, b128 reads <=2-way (free).
// T14: next chunk's global loads issued right after stage-barrier.
#define CSTEP 64
__global__ __launch_bounds__(256) void proj_mfma(
    const float* __restrict__ xl, const float* __restrict__ xh,
    const float* __restrict__ Wq, const float* __restrict__ bq,
    const float* __restrict__ Wk, const float* __restrict__ bk,
    const float* __restrict__ Wv, const float* __restrict__ bv,
    unsigned short* __restrict__ Qt, unsigned short* __restrict__ Kt,
    unsigned short* __restrict__ Vt)
{
    const int proj = blockIdx.z;
    const int b    = blockIdx.y;
    const int n0   = blockIdx.x * 64;
    const int tid  = threadIdx.x;
    const int wv   = tid >> 6;          // wave id 0..3
    const int lane = tid & 63;
    const int lo   = lane & 15;
    const int hi   = lane >> 4;         // 0..3
    const int hi8  = hi * 8;

    __shared__ unsigned short XtHi[64][72];
    __shared__ unsigned short XtLo[64][72];

    const int tS = tid & 7;         // staging token-group 0..7
    const int t8 = tS * 8;          // token offset 0..56
    const int cR = tid >> 3;        // staging chan 0..31 (+32 for slice 1)

    const float* X; int C;
    if (proj == 0) { X = xh; C = CHIGH; } else { X = xl; C = CLOW; }

    float4 pf[2][2];                // prefetch regs: [slice][half]

    #define LOADX(C0)                                                            \
        {                                                                        \
            _Pragma("unroll")                                                    \
            for (int s = 0; s < 2; ++s) {                                        \
                const float* src = X + ((size_t)b*C + (C0) + cR + 32*s)*N + n0 + t8; \
                pf[s][0] = *(const float4*)src;                                  \
                pf[s][1] = *(const float4*)(src + 4);                            \
            }                                                                    \
        }

    #define STAGE()                                                              \
        {                                                                        \
            _Pragma("unroll")                                                    \
            for (int s = 0; s < 2; ++s) {                                        \
                const int colx = (cR + 32*s) ^ (tS << 3);                        \
                float vv[8] = {pf[s][0].x, pf[s][0].y, pf[s][0].z, pf[s][0].w,   \
                               pf[s][1].x, pf[s][1].y, pf[s][1].z, pf[s][1].w};  \
                _Pragma("unroll")                                                \
                for (int i = 0; i < 8; ++i) {                                    \
                    short h_, l_;                                                \
                    bfsplit(vv[i], &h_, &l_);                                    \
                    XtHi[t8 + i][colx] = (unsigned short)h_;                     \
                    XtLo[t8 + i][colx] = (unsigned short)l_;                     \
                }                                                                \
            }                                                                    \
        }

    #define WSPLITLD(WP, AH, AL)                                                 \
        {                                                                        \
            float4 w0 = *(const float4*)(WP);                                    \
            float4 w1 = *(const float4*)((WP) + 4);                              \
            float ww[8] = {w0.x,w0.y,w0.z,w0.w,w1.x,w1.y,w1.z,w1.w};             \
            _Pragma("unroll")                                                    \
            for (int i = 0; i < 8; ++i) {                                        \
                short h_, l_;                                                    \
                bfsplit(ww[i], &h_, &l_);                                        \
                AH[i] = h_; AL[i] = l_;                                          \
            }                                                                    \
        }

    // fragment-store offset (layout comment above)
    const size_t kqFragOff = (size_t)((((wv*2 + (hi>>1)) & 3)*16 + lo)*8 + (hi&1)*4);

    if (proj == 0) {
        // ---------- Q ----------
        f32x4 acc[4];
        #pragma unroll
        for (int t = 0; t < 4; ++t)
            #pragma unroll
            for (int r = 0; r < 4; ++r) acc[t][r] = bq[wv*16 + hi*4 + r];

        LOADX(0)
        for (int c0 = 0; c0 < CHIGH; c0 += CSTEP) {
            STAGE()
            __syncthreads();
            if (c0 + CSTEP < CHIGH) LOADX(c0 + CSTEP)

            #pragma unroll
            for (int m = 0; m < 2; ++m) {
                bf16x8 ah, al;
                const float* wp = Wq + (size_t)(wv*16 + lo)*CHIGH + c0 + m*32 + hi8;
                WSPLITLD(wp, ah, al)
                #pragma unroll
                for (int tt = 0; tt < 4; ++tt) {
                    const int cx = (m*32 + hi8) ^ ((2*tt + (lo >> 3)) << 3);
                    bf16x8 xhv = *(const bf16x8*)&XtHi[tt*16 + lo][cx];
                    bf16x8 xlv = *(const bf16x8*)&XtLo[tt*16 + lo][cx];
                    acc[tt] = __builtin_amdgcn_mfma_f32_16x16x32_bf16(ah, xhv, acc[tt], 0, 0, 0);
                    acc[tt] = __builtin_amdgcn_mfma_f32_16x16x32_bf16(ah, xlv, acc[tt], 0, 0, 0);
                    acc[tt] = __builtin_amdgcn_mfma_f32_16x16x32_bf16(al, xhv, acc[tt], 0, 0, 0);
                }
            }
            __syncthreads();
        }
        const float qs = 1.4426950408889634f;   // log2(e): attn uses raw exp2
        #pragma unroll
        for (int t = 0; t < 4; ++t) {
            bf16x4 o;
            #pragma unroll
            for (int r = 0; r < 4; ++r) o[r] = (short)f2bf(acc[t][r] * qs);
            size_t base = (((size_t)b*256 + (n0>>4) + t)*2 + (wv>>1))*512;
            *(bf16x4*)&Qt[base + kqFragOff] = o;
        }
    } else {
        // ---------- K + V fused (stage xl once) ----------
        f32x4 accK[4], accV[4];
        #pragma unroll
        for (int t = 0; t < 4; ++t)
            #pragma unroll
            for (int r = 0; r < 4; ++r) {
                accK[t][r] = bk[wv*16 + hi*4 + r];
                accV[t][r] = bv[wv*16 + hi*4 + r];
            }

        LOADX(0)
        for (int c0 = 0; c0 < CLOW; c0 += CSTEP) {
            STAGE()
            __syncthreads();
            if (c0 + CSTEP < CLOW) LOADX(c0 + CSTEP)

            #pragma unroll
            for (int m = 0; m < 2; ++m) {
                bf16x8 ahk, alk, ahv, alv;
                const float* wpk = Wk + (size_t)(wv*16 + lo)*CLOW + c0 + m*32 + hi8;
                const float* wpv = Wv + (size_t)(wv*16 + lo)*CLOW + c0 + m*32 + hi8;
                WSPLITLD(wpk, ahk, alk)
                WSPLITLD(wpv, ahv, alv)
                #pragma unroll
                for (int tt = 0; tt < 4; ++tt) {
                    const int cx = (m*32 + hi8) ^ ((2*tt + (lo >> 3)) << 3);
                    bf16x8 xhv = *(const bf16x8*)&XtHi[tt*16 + lo][cx];
                    bf16x8 xlv = *(const bf16x8*)&XtLo[tt*16 + lo][cx];
                    accK[tt] = __builtin_amdgcn_mfma_f32_16x16x32_bf16(ahk, xhv, accK[tt], 0, 0, 0);
                    accK[tt] = __builtin_amdgcn_mfma_f32_16x16x32_bf16(ahk, xlv, accK[tt], 0, 0, 0);
                    accK[tt] = __builtin_amdgcn_mfma_f32_16x16x32_bf16(alk, xhv, accK[tt], 0, 0, 0);
                    accV[tt] = __builtin_amdgcn_mfma_f32_16x16x32_bf16(ahv, xhv, accV[tt], 0, 0, 0);
                    accV[tt] = __builtin_amdgcn_mfma_f32_16x16x32_bf16(ahv, xlv, accV[tt], 0, 0, 0);
                    accV[tt] = __builtin_amdgcn_mfma_f32_16x16x32_bf16(alv, xhv, accV[tt], 0, 0, 0);
                }
            }
            __syncthreads();
        }

        #pragma unroll
        for (int t = 0; t < 4; ++t) {
            // K fragment-major store
            bf16x4 o;
            #pragma unroll
            for (int r = 0; r < 4; ++r) o[r] = (short)f2bf(accK[t][r]);
            size_t kbase = (((size_t)b*256 + (n0>>4) + t)*2 + (wv>>1))*512;
            *(bf16x4*)&Kt[kbase + kqFragOff] = o;

            // V fragment-major store: chan = wv*16+hi*4+r, kv = n0+t*16+lo
            const int kvtile = (n0 >> 5) + (t >> 1);
            const int hi_f   = (t & 1)*2 + (lo >> 3);
            size_t vbase = ((size_t)b*128 + kvtile)*2048 + (size_t)wv*512
                         + (size_t)hi_f*128 + (size_t)(lo & 7);
            #pragma unroll
            for (int r = 0; r < 4; ++r)
                Vt[vbase + (size_t)(hi*4 + r)*8] = f2bf(accV[t][r]);
        }
    }
    #undef LOADX
    #undef STAGE
    #undef WSPLITLD
}

// ---------------- Flash attention: QT=4, 8 waves, kv-split-8, fragment-major loads --
// Grid = 256 blocks (1/CU). xcd = bid&7; batch = xcd>>1 (XCD-affinity -> K/V L2-res).
// Block = 8 waves (512 thr) sharing q-rows [q0, q0+64); wave w owns kv [w*512, +512).
// All K/V/Q loads are base + lane*16B (fragment-major) -> fully coalesced.
#define WSPLIT 8
#define QT 4
__global__ __launch_bounds__(512) void attn(
    const unsigned short* __restrict__ Qt,
    const unsigned short* __restrict__ Kt,
    const unsigned short* __restrict__ Vt,
    float* __restrict__ ctx)
{
    const int bid = blockIdx.x;
    const int xcd = bid & 7;
    const int b   = xcd >> 1;                          // batch <- XCD pair
    const int q0  = ((bid >> 3) * 2 + (xcd & 1)) * 64; // q-tile base (64 rows)

    const int tid  = threadIdx.x;
    const int wv   = tid >> 6;    // 0..7
    const int lane = tid & 63;
    const int lo   = lane & 15;
    const int hi   = lane >> 4;   // 0..3

    __shared__ float Olds[WSPLIT][64][68];   // 139 KB; pad 68 -> 272B row stride
    __shared__ float llds[WSPLIT][64];

    const unsigned short* Kb = Kt + (size_t)b*N*KC;
    const unsigned short* Vb = Vt + (size_t)b*VC*N;
    const unsigned short* Qb = Qt + (size_t)b*N*KC;

    // Q fragments (fragment-major: one dwordx4 per lane)
    bf16x8 qf[2][QT];
    #pragma unroll
    for (int qt = 0; qt < QT; ++qt) {
        #pragma unroll
        for (int kt = 0; kt < 2; ++kt)
            qf[kt][qt] = *(const bf16x8*)&Qb[(((size_t)(q0>>4) + qt)*2 + kt)*512 + lane*8];
    }

    f32x4 O[4][QT] = {};           // [v-subtile][q-subtile]
    float l_run[QT] = {};

    const int kv0   = wv * (N/WSPLIT);
    const int kvend = kv0 + (N/WSPLIT);

    for (int kv = kv0; kv < kvend; kv += 32) {
        // ---- K A-frags + V B-frags, all coalesced lane*16B loads ----
        bf16x8 ka[2][2], va[4];
        #pragma unroll
        for (int j = 0; j < 2; ++j)
            #pragma unroll
            for (int m = 0; m < 2; ++m)
                ka[j][m] = *(const bf16x8*)&Kb[(((size_t)(kv>>4) + j)*2 + m)*512 + lane*8];
        #pragma unroll
        for (int vt = 0; vt < 4; ++vt)
            va[vt] = *(const bf16x8*)&Vb[((size_t)(kv>>5))*2048 + vt*512 + lane*8];

        #pragma unroll
        for (int qt = 0; qt < QT; ++qt) {
            // ---- S^T = K · Q^T : lane(hi,lo) reg r = P^T[4hi+r][q=lo] ----
            f32x4 st[2];
            #pragma unroll
            for (int j = 0; j < 2; ++j) {
                f32x4 z = {};
                z     = __builtin_amdgcn_mfma_f32_16x16x32_bf16(ka[j][0], qf[0][qt], z, 0, 0, 0);
                st[j] = __builtin_amdgcn_mfma_f32_16x16x32_bf16(ka[j][1], qf[1][qt], z, 0, 0, 0);
            }
            // ---- p = 2^s (Q pre-scaled by log2e); in-lane bf16 pack ----
            uint32_t pk[2][2];
            #pragma unroll
            for (int j = 0; j < 2; ++j) {
                float p0 = EXP2(st[j][0]);
                float p1 = EXP2(st[j][1]);
                float p2 = EXP2(st[j][2]);
                float p3 = EXP2(st[j][3]);
                l_run[qt] += (p0 + p1) + (p2 + p3);
                pk[j][0] = packbf2(p0, p1);
                pk[j][1] = packbf2(p2, p3);
            }
            // ---- P^T(D-layout) -> P(A-frag) via 8 shfl + selects (R4-validated) ----
            union { int w[4]; bf16x8 v; } pa;
            #pragma unroll
            for (int w = 0; w < 4; ++w) {
                int src = (2*(hi & 1) + (w >> 1))*16 + lo;
                int t0 = __shfl((int)pk[0][w & 1], src);
                int t1 = __shfl((int)pk[1][w & 1], src);
                pa.w[w] = (hi < 2) ? t0 : t1;
            }
            // ---- PV ----
            #pragma unroll
            for (int vt = 0; vt < 4; ++vt)
                O[vt][qt] = __builtin_amdgcn_mfma_f32_16x16x32_bf16(pa.v, va[vt], O[vt][qt], 0, 0, 0);
        }
    }

    // ---- reduce l across the 4 hi-groups; every lane gets l[q=lo] ----
    #pragma unroll
    for (int qt = 0; qt < QT; ++qt) {
        float s = l_run[qt];
        s += __shfl_xor(s, 16);
        s += __shfl_xor(s, 32);
        l_run[qt] = s;
    }

    // ---- write per-wave partials ----
    #pragma unroll
    for (int qt = 0; qt < QT; ++qt) {
        #pragma unroll
        for (int vt = 0; vt < 4; ++vt)
            #pragma unroll
            for (int r = 0; r < 4; ++r)
                Olds[wv][qt*16 + hi*4 + r][vt*16 + lo] = O[vt][qt][r];
        if (lane < 16) llds[wv][qt*16 + lo] = l_run[qt];
    }
    __syncthreads();

    // ---- combine kv-split partials, normalize, store (512 thr = 64 rows x 8 col8) ----
    {
        const int row = tid >> 3;         // 0..63
        const int c8  = (tid & 7) * 8;    // 0..56
        float L = 0.f;
        #pragma unroll
        for (int w = 0; w < WSPLIT; ++w) L += llds[w][row];
        float4 a0 = {0.f,0.f,0.f,0.f}, a1 = {0.f,0.f,0.f,0.f};
        #pragma unroll
        for (int w = 0; w < WSPLIT; ++w) {
            float4 o0 = *(const float4*)&Olds[w][row][c8];
            float4 o1 = *(const float4*)&Olds[w][row][c8 + 4];
            a0.x += o0.x; a0.y += o0.y; a0.z += o0.z; a0.w += o0.w;
            a1.x += o1.x; a1.y += o1.y; a1.z += o1.z; a1.w += o1.w;
        }
        float rL = 1.0f / L;
        a0.x *= rL; a0.y *= rL; a0.z *= rL; a0.w *= rL;
        a1.x *= rL; a1.y *= rL; a1.z *= rL; a1.w *= rL;
        float* cp = &ctx[((size_t)b*N + q0 + row)*VC + c8];
        *(float4*)(cp)     = a0;
        *(float4*)(cp + 4) = a1;
    }
}

// ---------------- Output projection + residual via split-bf16 MFMA ----------------
// Out[o][n] = sum_v Wo[o][v]*ctx[n][v] + bo[o] + xh[o][n]
// A-frag = Wo row-major (contiguous), B-frag = ctx token-major (contiguous) -> no LDS.
__global__ __launch_bounds__(256) void oproj_mfma(
    const float* __restrict__ ctx, const float* __restrict__ Wo,
    const float* __restrict__ bo, const float* __restrict__ xh,
    float* __restrict__ out)
{
    const int b    = blockIdx.y;
    const int n0   = blockIdx.x * 64;
    const int tid  = threadIdx.x;
    const int wv   = tid >> 6;          // wave -> chans [wv*64, +64)
    const int lane = tid & 63;
    const int lo   = lane & 15;
    const int hi   = lane >> 4;
    const int hi8  = hi * 8;

    for (int tt = 0; tt < 4; ++tt) {
        // ---- B-frags: ctx[n0+tt*16+lo][j*32+hi8 ..+8), split hi/lo ----
        bf16x8 bh[2], bl[2];
        const float* cp = ctx + ((size_t)b*N + n0 + tt*16 + lo)*VC + hi8;
        #pragma unroll
        for (int j = 0; j < 2; ++j) {
            float4 c0 = *(const float4*)(cp + j*32);
            float4 c1 = *(const float4*)(cp + j*32 + 4);
            float cc[8] = {c0.x,c0.y,c0.z,c0.w,c1.x,c1.y,c1.z,c1.w};
            #pragma unroll
            for (int i = 0; i < 8; ++i) {
                short h_, l_;
                bfsplit(cc[i], &h_, &l_);
                bh[j][i] = h_;
                bl[j][i] = l_;
            }
        }
        #pragma unroll
        for (int ct = 0; ct < 4; ++ct) {
            const int chan0 = wv*64 + ct*16;
            // ---- A-frags: Wo[chan0+lo][j*32+hi8 ..+8), split hi/lo (L1-resident) ----
            bf16x8 ah[2], al[2];
            const float* wp = Wo + (size_t)(chan0 + lo)*VC + hi8;
            #pragma unroll
            for (int j = 0; j < 2; ++j) {
                float4 w0 = *(const float4*)(wp + j*32);
                float4 w1 = *(const float4*)(wp + j*32 + 4);
                float ww[8] = {w0.x,w0.y,w0.z,w0.w,w1.x,w1.y,w1.z,w1.w};
                #pragma unroll
                for (int i = 0; i < 8; ++i) {
                    short h_, l_;
                    bfsplit(ww[i], &h_, &l_);
                    ah[j][i] = h_;
                    al[j][i] = l_;
                }
            }
            f32x4 acc;
            #pragma unroll
            for (int r = 0; r < 4; ++r) acc[r] = bo[chan0 + hi*4 + r];
            #pragma unroll
            for (int j = 0; j < 2; ++j) {
                acc = __builtin_amdgcn_mfma_f32_16x16x32_bf16(ah[j], bh[j], acc, 0, 0, 0);
                acc = __builtin_amdgcn_mfma_f32_16x16x32_bf16(ah[j], bl[j], acc, 0, 0, 0);
                acc = __builtin_amdgcn_mfma_f32_16x16x32_bf16(al[j], bh[j], acc, 0, 0, 0);
            }
            // ---- residual + store: D[row=4hi+r][col=lo], row=chan, col=token ----
            #pragma unroll
            for (int r = 0; r < 4; ++r) {
                size_t idx = ((size_t)b*CHIGH + chan0 + hi*4 + r)*N + n0 + tt*16 + lo;
                out[idx] = acc[r] + xh[idx];
            }
        }
    }
}

extern "C" void kernel_launch(void* const* d_in, const int* in_sizes, int n_in,
                              void* d_out, int out_size, void* d_ws, size_t ws_size,
                              hipStream_t stream) {
    const float* xl = (const float*)d_in[0];
    const float* xh = (const float*)d_in[1];
    const float* Wq = (const float*)d_in[2];
    const float* bq = (const float*)d_in[3];
    const float* Wk = (const float*)d_in[4];
    const float* bk = (const float*)d_in[5];
    const float* Wv = (const float*)d_in[6];
    const float* bv = (const float*)d_in[7];
    const float* Wo = (const float*)d_in[8];
    const float* bo = (const float*)d_in[9];
    float* out = (float*)d_out;

    unsigned short* Qt = (unsigned short*)d_ws;                 // [B][N*64] bf16 frag-major (x log2e)
    unsigned short* Kt = Qt + (size_t)B*N*KC;                   // [B][N*64] bf16 frag-major
    unsigned short* Vt = Kt + (size_t)B*N*KC;                   // [B][64*N] bf16 frag-major
    float*         ctxp = (float*)(Vt + (size_t)B*VC*N);        // [B][N][64] f32

    hipLaunchKernelGGL(proj_mfma, dim3(N/64, B, 2), dim3(256), 0, stream,
                       xl, xh, Wq, bq, Wk, bk, Wv, bv, Qt, Kt, Vt);
    hipLaunchKernelGGL(attn, dim3(256), dim3(512), 0, stream,
                       Qt, Kt, Vt, ctxp);
    hipLaunchKernelGGL(oproj_mfma, dim3(N/64, B), dim3(256), 0, stream,
                       ctxp, Wo, bo, xh, out);
}

// Round 13
// 70.216 us; speedup vs baseline: 2.0443x; 1.0864x over previous
//
#include <hip/hip_runtime.h>
#include <hip/hip_bf16.h>
#include <math.h>
#include <stdint.h>

#define B 4
#define CLOW 512
#define CHIGH 256
#define KC 64
#define VC 64
#define N 4096  // 64*64 tokens

typedef __attribute__((ext_vector_type(8))) short bf16x8;
typedef __attribute__((ext_vector_type(4))) short bf16x4;
typedef __attribute__((ext_vector_type(4))) float f32x4;

__device__ inline unsigned short f2bf(float f) {
    union { float f; uint32_t u; } v; v.f = f;
    uint32_t u = v.u;
    u += 0x7fff + ((u >> 16) & 1);   // RNE
    return (unsigned short)(u >> 16);
}
__device__ inline float bf2f(unsigned short h) {
    union { uint32_t u; float f; } v; v.u = ((uint32_t)h) << 16;
    return v.f;
}
__device__ inline uint32_t packbf2(float a, float b) {
    union { __hip_bfloat16 h; unsigned short u; } ca, cb;
    ca.h = __float2bfloat16(a);
    cb.h = __float2bfloat16(b);
    return (uint32_t)ca.u | ((uint32_t)cb.u << 16);
}
__device__ inline void bfsplit(float x, short* hi, short* lo) {
    union { __hip_bfloat16 h; unsigned short u; } c, d;
    c.h = __float2bfloat16(x);
    d.h = __float2bfloat16(x - __bfloat162float(c.h));
    *hi = (short)c.u; *lo = (short)d.u;
}

#if __has_builtin(__builtin_amdgcn_exp2f)
#define EXP2(x) __builtin_amdgcn_exp2f(x)
#else
#define EXP2(x) exp2f(x)
#endif

// ================= Fragment-major layouts (attn loads are base + lane*16B) ====
// Kf[b][tile16][m][lane][8] : elem K[tile*16+lo][m*32+hi*8+e],   lane = hi*16+lo
// Qf[b][tile16][kt][lane][8]: elem Q[tile*16+lo][kt*32+hi*8+e]   (pre-scaled log2e)
// Vf[b][tile32][vt][lane][8]: elem V[chan=vt*16+lo][tile*32+hi*8+e]

// ---------------- QKV projection via split-bf16 MFMA, 32-token tiles ----------------
// z=0: Q from xh (C=256). z=1: K AND V fused from xl (C=512), xl staged once.
// 32-token tiles -> grid 1024 blocks = 4 blocks/CU = 4 waves/SIMD (occupancy fix).
// CSTEP=64 chans/chunk; LDS stride 72 shorts; block-XOR swizzle col^=(row>>3)<<3.
#define CSTEP 64
__global__ __launch_bounds__(256) void proj_mfma(
    const float* __restrict__ xl, const float* __restrict__ xh,
    const float* __restrict__ Wq, const float* __restrict__ bq,
    const float* __restrict__ Wk, const float* __restrict__ bk,
    const float* __restrict__ Wv, const float* __restrict__ bv,
    unsigned short* __restrict__ Qt, unsigned short* __restrict__ Kt,
    unsigned short* __restrict__ Vt)
{
    const int proj = blockIdx.z;
    const int b    = blockIdx.y;
    const int bidx = blockIdx.x;
    const int n0   = bidx * 32;
    const int tid  = threadIdx.x;
    const int wv   = tid >> 6;          // wave id 0..3
    const int lane = tid & 63;
    const int lo   = lane & 15;
    const int hi   = lane >> 4;         // 0..3
    const int hi8  = hi * 8;

    __shared__ unsigned short XtHi[32][72];
    __shared__ unsigned short XtLo[32][72];

    const int tS = tid & 3;         // staging token-group 0..3
    const int t8 = tS * 8;          // token offset 0..24
    const int cR = tid >> 2;        // staging chan 0..63

    const float* X; int C;
    if (proj == 0) { X = xh; C = CHIGH; } else { X = xl; C = CLOW; }

    float4 pf0, pf1;                // prefetch regs

    #define LOADX(C0)                                                            \
        {                                                                        \
            const float* src = X + ((size_t)b*C + (C0) + cR)*N + n0 + t8;        \
            pf0 = *(const float4*)src;                                           \
            pf1 = *(const float4*)(src + 4);                                     \
        }

    #define STAGE()                                                              \
        {                                                                        \
            const int colx = cR ^ (tS << 3);                                     \
            float vv[8] = {pf0.x, pf0.y, pf0.z, pf0.w,                           \
                           pf1.x, pf1.y, pf1.z, pf1.w};                          \
            _Pragma("unroll")                                                    \
            for (int i = 0; i < 8; ++i) {                                        \
                short h_, l_;                                                    \
                bfsplit(vv[i], &h_, &l_);                                        \
                XtHi[t8 + i][colx] = (unsigned short)h_;                         \
                XtLo[t8 + i][colx] = (unsigned short)l_;                         \
            }                                                                    \
        }

    #define WSPLITLD(WP, AH, AL)                                                 \
        {                                                                        \
            float4 w0 = *(const float4*)(WP);                                    \
            float4 w1 = *(const float4*)((WP) + 4);                              \
            float ww[8] = {w0.x,w0.y,w0.z,w0.w,w1.x,w1.y,w1.z,w1.w};             \
            _Pragma("unroll")                                                    \
            for (int i = 0; i < 8; ++i) {                                        \
                short h_, l_;                                                    \
                bfsplit(ww[i], &h_, &l_);                                        \
                AH[i] = h_; AL[i] = l_;                                          \
            }                                                                    \
        }

    // fragment-store offset (layout comment above)
    const size_t kqFragOff = (size_t)((((wv*2 + (hi>>1)) & 3)*16 + lo)*8 + (hi&1)*4);

    if (proj == 0) {
        // ---------- Q ----------
        f32x4 acc[2];
        #pragma unroll
        for (int t = 0; t < 2; ++t)
            #pragma unroll
            for (int r = 0; r < 4; ++r) acc[t][r] = bq[wv*16 + hi*4 + r];

        LOADX(0)
        for (int c0 = 0; c0 < CHIGH; c0 += CSTEP) {
            STAGE()
            __syncthreads();
            if (c0 + CSTEP < CHIGH) LOADX(c0 + CSTEP)

            #pragma unroll
            for (int m = 0; m < 2; ++m) {
                bf16x8 ah, al;
                const float* wp = Wq + (size_t)(wv*16 + lo)*CHIGH + c0 + m*32 + hi8;
                WSPLITLD(wp, ah, al)
                #pragma unroll
                for (int tt = 0; tt < 2; ++tt) {
                    const int cx = (m*32 + hi8) ^ ((2*tt + (lo >> 3)) << 3);
                    bf16x8 xhv = *(const bf16x8*)&XtHi[tt*16 + lo][cx];
                    bf16x8 xlv = *(const bf16x8*)&XtLo[tt*16 + lo][cx];
                    acc[tt] = __builtin_amdgcn_mfma_f32_16x16x32_bf16(ah, xhv, acc[tt], 0, 0, 0);
                    acc[tt] = __builtin_amdgcn_mfma_f32_16x16x32_bf16(ah, xlv, acc[tt], 0, 0, 0);
                    acc[tt] = __builtin_amdgcn_mfma_f32_16x16x32_bf16(al, xhv, acc[tt], 0, 0, 0);
                }
            }
            __syncthreads();
        }
        const float qs = 1.4426950408889634f;   // log2(e): attn uses raw exp2
        #pragma unroll
        for (int t = 0; t < 2; ++t) {
            bf16x4 o;
            #pragma unroll
            for (int r = 0; r < 4; ++r) o[r] = (short)f2bf(acc[t][r] * qs);
            size_t base = (((size_t)b*256 + 2*bidx + t)*2 + (wv>>1))*512;
            *(bf16x4*)&Qt[base + kqFragOff] = o;
        }
    } else {
        // ---------- K + V fused (stage xl once) ----------
        f32x4 accK[2], accV[2];
        #pragma unroll
        for (int t = 0; t < 2; ++t)
            #pragma unroll
            for (int r = 0; r < 4; ++r) {
                accK[t][r] = bk[wv*16 + hi*4 + r];
                accV[t][r] = bv[wv*16 + hi*4 + r];
            }

        LOADX(0)
        for (int c0 = 0; c0 < CLOW; c0 += CSTEP) {
            STAGE()
            __syncthreads();
            if (c0 + CSTEP < CLOW) LOADX(c0 + CSTEP)

            #pragma unroll
            for (int m = 0; m < 2; ++m) {
                bf16x8 ahk, alk, ahv, alv;
                const float* wpk = Wk + (size_t)(wv*16 + lo)*CLOW + c0 + m*32 + hi8;
                const float* wpv = Wv + (size_t)(wv*16 + lo)*CLOW + c0 + m*32 + hi8;
                WSPLITLD(wpk, ahk, alk)
                WSPLITLD(wpv, ahv, alv)
                #pragma unroll
                for (int tt = 0; tt < 2; ++tt) {
                    const int cx = (m*32 + hi8) ^ ((2*tt + (lo >> 3)) << 3);
                    bf16x8 xhv = *(const bf16x8*)&XtHi[tt*16 + lo][cx];
                    bf16x8 xlv = *(const bf16x8*)&XtLo[tt*16 + lo][cx];
                    accK[tt] = __builtin_amdgcn_mfma_f32_16x16x32_bf16(ahk, xhv, accK[tt], 0, 0, 0);
                    accK[tt] = __builtin_amdgcn_mfma_f32_16x16x32_bf16(ahk, xlv, accK[tt], 0, 0, 0);
                    accK[tt] = __builtin_amdgcn_mfma_f32_16x16x32_bf16(alk, xhv, accK[tt], 0, 0, 0);
                    accV[tt] = __builtin_amdgcn_mfma_f32_16x16x32_bf16(ahv, xhv, accV[tt], 0, 0, 0);
                    accV[tt] = __builtin_amdgcn_mfma_f32_16x16x32_bf16(ahv, xlv, accV[tt], 0, 0, 0);
                    accV[tt] = __builtin_amdgcn_mfma_f32_16x16x32_bf16(alv, xhv, accV[tt], 0, 0, 0);
                }
            }
            __syncthreads();
        }

        #pragma unroll
        for (int t = 0; t < 2; ++t) {
            // K fragment-major store
            bf16x4 o;
            #pragma unroll
            for (int r = 0; r < 4; ++r) o[r] = (short)f2bf(accK[t][r]);
            size_t kbase = (((size_t)b*256 + 2*bidx + t)*2 + (wv>>1))*512;
            *(bf16x4*)&Kt[kbase + kqFragOff] = o;

            // V fragment-major store: chan = wv*16+hi*4+r, kv = n0+t*16+lo
            const int hi_f = t*2 + (lo >> 3);
            size_t vbase = ((size_t)b*128 + bidx)*2048 + (size_t)wv*512
                         + (size_t)hi_f*128 + (size_t)(lo & 7);
            #pragma unroll
            for (int r = 0; r < 4; ++r)
                Vt[vbase + (size_t)(hi*4 + r)*8] = f2bf(accV[t][r]);
        }
    }
    #undef LOADX
    #undef STAGE
    #undef WSPLITLD
}

// ---------------- Flash attention: QT=4, 8 waves, kv-split-8, fragment-major loads --
// Grid = 256 blocks (1/CU). xcd = bid&7; batch = xcd>>1 (XCD-affinity -> K/V L2-res).
// Block = 8 waves (512 thr) sharing q-rows [q0, q0+64); wave w owns kv [w*512, +512).
// All K/V/Q loads are base + lane*16B (fragment-major) -> fully coalesced.
#define WSPLIT 8
#define QT 4
__global__ __launch_bounds__(512) void attn(
    const unsigned short* __restrict__ Qt,
    const unsigned short* __restrict__ Kt,
    const unsigned short* __restrict__ Vt,
    float* __restrict__ ctx)
{
    const int bid = blockIdx.x;
    const int xcd = bid & 7;
    const int b   = xcd >> 1;                          // batch <- XCD pair
    const int q0  = ((bid >> 3) * 2 + (xcd & 1)) * 64; // q-tile base (64 rows)

    const int tid  = threadIdx.x;
    const int wv   = tid >> 6;    // 0..7
    const int lane = tid & 63;
    const int lo   = lane & 15;
    const int hi   = lane >> 4;   // 0..3

    __shared__ float Olds[WSPLIT][64][68];   // 139 KB; pad 68 -> 272B row stride
    __shared__ float llds[WSPLIT][64];

    const unsigned short* Kb = Kt + (size_t)b*N*KC;
    const unsigned short* Vb = Vt + (size_t)b*VC*N;
    const unsigned short* Qb = Qt + (size_t)b*N*KC;

    // Q fragments (fragment-major: one dwordx4 per lane)
    bf16x8 qf[2][QT];
    #pragma unroll
    for (int qt = 0; qt < QT; ++qt) {
        #pragma unroll
        for (int kt = 0; kt < 2; ++kt)
            qf[kt][qt] = *(const bf16x8*)&Qb[(((size_t)(q0>>4) + qt)*2 + kt)*512 + lane*8];
    }

    f32x4 O[4][QT] = {};           // [v-subtile][q-subtile]
    float l_run[QT] = {};

    const int kv0   = wv * (N/WSPLIT);
    const int kvend = kv0 + (N/WSPLIT);

    for (int kv = kv0; kv < kvend; kv += 32) {
        // ---- K A-frags + V B-frags, all coalesced lane*16B loads ----
        bf16x8 ka[2][2], va[4];
        #pragma unroll
        for (int j = 0; j < 2; ++j)
            #pragma unroll
            for (int m = 0; m < 2; ++m)
                ka[j][m] = *(const bf16x8*)&Kb[(((size_t)(kv>>4) + j)*2 + m)*512 + lane*8];
        #pragma unroll
        for (int vt = 0; vt < 4; ++vt)
            va[vt] = *(const bf16x8*)&Vb[((size_t)(kv>>5))*2048 + vt*512 + lane*8];

        #pragma unroll
        for (int qt = 0; qt < QT; ++qt) {
            // ---- S^T = K · Q^T : lane(hi,lo) reg r = P^T[4hi+r][q=lo] ----
            f32x4 st[2];
            #pragma unroll
            for (int j = 0; j < 2; ++j) {
                f32x4 z = {};
                z     = __builtin_amdgcn_mfma_f32_16x16x32_bf16(ka[j][0], qf[0][qt], z, 0, 0, 0);
                st[j] = __builtin_amdgcn_mfma_f32_16x16x32_bf16(ka[j][1], qf[1][qt], z, 0, 0, 0);
            }
            // ---- p = 2^s (Q pre-scaled by log2e); in-lane bf16 pack ----
            uint32_t pk[2][2];
            #pragma unroll
            for (int j = 0; j < 2; ++j) {
                float p0 = EXP2(st[j][0]);
                float p1 = EXP2(st[j][1]);
                float p2 = EXP2(st[j][2]);
                float p3 = EXP2(st[j][3]);
                l_run[qt] += (p0 + p1) + (p2 + p3);
                pk[j][0] = packbf2(p0, p1);
                pk[j][1] = packbf2(p2, p3);
            }
            // ---- P^T(D-layout) -> P(A-frag) via 8 shfl + selects (R4-validated) ----
            union { int w[4]; bf16x8 v; } pa;
            #pragma unroll
            for (int w = 0; w < 4; ++w) {
                int src = (2*(hi & 1) + (w >> 1))*16 + lo;
                int t0 = __shfl((int)pk[0][w & 1], src);
                int t1 = __shfl((int)pk[1][w & 1], src);
                pa.w[w] = (hi < 2) ? t0 : t1;
            }
            // ---- PV ----
            #pragma unroll
            for (int vt = 0; vt < 4; ++vt)
                O[vt][qt] = __builtin_amdgcn_mfma_f32_16x16x32_bf16(pa.v, va[vt], O[vt][qt], 0, 0, 0);
        }
    }

    // ---- reduce l across the 4 hi-groups; every lane gets l[q=lo] ----
    #pragma unroll
    for (int qt = 0; qt < QT; ++qt) {
        float s = l_run[qt];
        s += __shfl_xor(s, 16);
        s += __shfl_xor(s, 32);
        l_run[qt] = s;
    }

    // ---- write per-wave partials ----
    #pragma unroll
    for (int qt = 0; qt < QT; ++qt) {
        #pragma unroll
        for (int vt = 0; vt < 4; ++vt)
            #pragma unroll
            for (int r = 0; r < 4; ++r)
                Olds[wv][qt*16 + hi*4 + r][vt*16 + lo] = O[vt][qt][r];
        if (lane < 16) llds[wv][qt*16 + lo] = l_run[qt];
    }
    __syncthreads();

    // ---- combine kv-split partials, normalize, store (512 thr = 64 rows x 8 col8) ----
    {
        const int row = tid >> 3;         // 0..63
        const int c8  = (tid & 7) * 8;    // 0..56
        float L = 0.f;
        #pragma unroll
        for (int w = 0; w < WSPLIT; ++w) L += llds[w][row];
        float4 a0 = {0.f,0.f,0.f,0.f}, a1 = {0.f,0.f,0.f,0.f};
        #pragma unroll
        for (int w = 0; w < WSPLIT; ++w) {
            float4 o0 = *(const float4*)&Olds[w][row][c8];
            float4 o1 = *(const float4*)&Olds[w][row][c8 + 4];
            a0.x += o0.x; a0.y += o0.y; a0.z += o0.z; a0.w += o0.w;
            a1.x += o1.x; a1.y += o1.y; a1.z += o1.z; a1.w += o1.w;
        }
        float rL = 1.0f / L;
        a0.x *= rL; a0.y *= rL; a0.z *= rL; a0.w *= rL;
        a1.x *= rL; a1.y *= rL; a1.z *= rL; a1.w *= rL;
        float* cp = &ctx[((size_t)b*N + q0 + row)*VC + c8];
        *(float4*)(cp)     = a0;
        *(float4*)(cp + 4) = a1;
    }
}

// ---------------- Output projection + residual via split-bf16 MFMA, 16-token tiles --
// Out[o][n] = sum_v Wo[o][v]*ctx[n][v] + bo[o] + xh[o][n]
// 16-token tiles -> grid 1024 blocks = 4 blocks/CU = 4 waves/SIMD (occupancy fix);
// A-frags built once per ct (no token-tile loop).
__global__ __launch_bounds__(256) void oproj_mfma(
    const float* __restrict__ ctx, const float* __restrict__ Wo,
    const float* __restrict__ bo, const float* __restrict__ xh,
    float* __restrict__ out)
{
    const int b    = blockIdx.y;
    const int n0   = blockIdx.x * 16;
    const int tid  = threadIdx.x;
    const int wv   = tid >> 6;          // wave -> chans [wv*64, +64)
    const int lane = tid & 63;
    const int lo   = lane & 15;
    const int hi   = lane >> 4;
    const int hi8  = hi * 8;

    // ---- B-frags: ctx[n0+lo][j*32+hi8 ..+8), split hi/lo ----
    bf16x8 bh[2], bl[2];
    const float* cp = ctx + ((size_t)b*N + n0 + lo)*VC + hi8;
    #pragma unroll
    for (int j = 0; j < 2; ++j) {
        float4 c0 = *(const float4*)(cp + j*32);
        float4 c1 = *(const float4*)(cp + j*32 + 4);
        float cc[8] = {c0.x,c0.y,c0.z,c0.w,c1.x,c1.y,c1.z,c1.w};
        #pragma unroll
        for (int i = 0; i < 8; ++i) {
            short h_, l_;
            bfsplit(cc[i], &h_, &l_);
            bh[j][i] = h_;
            bl[j][i] = l_;
        }
    }
    #pragma unroll
    for (int ct = 0; ct < 4; ++ct) {
        const int chan0 = wv*64 + ct*16;
        // ---- A-frags: Wo[chan0+lo][j*32+hi8 ..+8), split hi/lo (L1-resident) ----
        bf16x8 ah[2], al[2];
        const float* wp = Wo + (size_t)(chan0 + lo)*VC + hi8;
        #pragma unroll
        for (int j = 0; j < 2; ++j) {
            float4 w0 = *(const float4*)(wp + j*32);
            float4 w1 = *(const float4*)(wp + j*32 + 4);
            float ww[8] = {w0.x,w0.y,w0.z,w0.w,w1.x,w1.y,w1.z,w1.w};
            #pragma unroll
            for (int i = 0; i < 8; ++i) {
                short h_, l_;
                bfsplit(ww[i], &h_, &l_);
                ah[j][i] = h_;
                al[j][i] = l_;
            }
        }
        f32x4 acc;
        #pragma unroll
        for (int r = 0; r < 4; ++r) acc[r] = bo[chan0 + hi*4 + r];
        #pragma unroll
        for (int j = 0; j < 2; ++j) {
            acc = __builtin_amdgcn_mfma_f32_16x16x32_bf16(ah[j], bh[j], acc, 0, 0, 0);
            acc = __builtin_amdgcn_mfma_f32_16x16x32_bf16(ah[j], bl[j], acc, 0, 0, 0);
            acc = __builtin_amdgcn_mfma_f32_16x16x32_bf16(al[j], bh[j], acc, 0, 0, 0);
        }
        // ---- residual + store: D[row=4hi+r][col=lo], row=chan, col=token ----
        #pragma unroll
        for (int r = 0; r < 4; ++r) {
            size_t idx = ((size_t)b*CHIGH + chan0 + hi*4 + r)*N + n0 + lo;
            out[idx] = acc[r] + xh[idx];
        }
    }
}

extern "C" void kernel_launch(void* const* d_in, const int* in_sizes, int n_in,
                              void* d_out, int out_size, void* d_ws, size_t ws_size,
                              hipStream_t stream) {
    const float* xl = (const float*)d_in[0];
    const float* xh = (const float*)d_in[1];
    const float* Wq = (const float*)d_in[2];
    const float* bq = (const float*)d_in[3];
    const float* Wk = (const float*)d_in[4];
    const float* bk = (const float*)d_in[5];
    const float* Wv = (const float*)d_in[6];
    const float* bv = (const float*)d_in[7];
    const float* Wo = (const float*)d_in[8];
    const float* bo = (const float*)d_in[9];
    float* out = (float*)d_out;

    unsigned short* Qt = (unsigned short*)d_ws;                 // [B][N*64] bf16 frag-major (x log2e)
    unsigned short* Kt = Qt + (size_t)B*N*KC;                   // [B][N*64] bf16 frag-major
    unsigned short* Vt = Kt + (size_t)B*N*KC;                   // [B][64*N] bf16 frag-major
    float*         ctxp = (float*)(Vt + (size_t)B*VC*N);        // [B][N][64] f32

    hipLaunchKernelGGL(proj_mfma, dim3(N/32, B, 2), dim3(256), 0, stream,
                       xl, xh, Wq, bq, Wk, bk, Wv, bv, Qt, Kt, Vt);
    hipLaunchKernelGGL(attn, dim3(256), dim3(512), 0, stream,
                       Qt, Kt, Vt, ctxp);
    hipLaunchKernelGGL(oproj_mfma, dim3(N/16, B), dim3(256), 0, stream,
                       ctxp, Wo, bo, xh, out);
}